// Round 3
// baseline (1384.192 us; speedup 1.0000x reference)
//
#include <hip/hip_runtime.h>
#include <hip/hip_bf16.h>
#include <cstdint>

typedef unsigned short u16;
typedef __attribute__((ext_vector_type(8))) _Float16 f16x8;
typedef __attribute__((ext_vector_type(4))) float f32x4;
typedef __attribute__((ext_vector_type(8))) unsigned short u16x8;

typedef const __attribute__((address_space(1))) void* gas1p;
typedef __attribute__((address_space(3))) void* las3p;

__device__ __forceinline__ void gld_lds16(const void* g, void* l) {
    __builtin_amdgcn_global_load_lds((gas1p)g, (las3p)l, 16, 0, 0);
}

__device__ __forceinline__ u16 f2h(float f) {
    _Float16 h = (_Float16)f;
    return __builtin_bit_cast(u16, h);
}

// ---------------- prep: x fp32 -> fp16 ----------------
__global__ void cvt_x_kernel(const float4* __restrict__ x, u16* __restrict__ xb) {
    size_t i = (size_t)blockIdx.x * blockDim.x + threadIdx.x;
    float4 a = x[2 * i];
    float4 b = x[2 * i + 1];
    u16x8 o;
    o[0] = f2h(a.x); o[1] = f2h(a.y); o[2] = f2h(a.z); o[3] = f2h(a.w);
    o[4] = f2h(b.x); o[5] = f2h(b.y); o[6] = f2h(b.z); o[7] = f2h(b.w);
    *(u16x8*)&xb[i * 8] = o;
}

// ---------------- prep: fused weight norm (one kernel per layer) ----------------
// block = 256 thr handles 64 cols; two passes over v (2nd pass L2-hot).
__global__ void wn_fused(const float* __restrict__ v, const float* __restrict__ g,
                         u16* __restrict__ wT, int K, int N) {
    int lane = threadIdx.x & 63;
    int tr = threadIdx.x >> 6;
    int n = blockIdx.x * 64 + lane;
    float s = 0.f;
    for (int k = tr; k < K; k += 4) {
        float x = v[(size_t)k * N + n];
        s += x * x;
    }
    __shared__ float red[4][64];
    __shared__ float sc[64];
    red[tr][lane] = s;
    __syncthreads();
    if (threadIdx.x < 64)
        sc[lane] = g[n] / sqrtf(red[0][lane] + red[1][lane] + red[2][lane] + red[3][lane]);
    __syncthreads();
    float scale = sc[lane];
    for (int k = tr; k < K; k += 4)
        wT[(size_t)n * K + k] = f2h(v[(size_t)k * N + n] * scale);
}

// ---------------- main GEMM: 256x256 tile, BK=64, 8 waves, 4-phase schedule ----
// A:[M,K] fp16 row-major, Bt:[N,K] fp16. C = act(A@B).
// Staging per tile t: P1: A(t+1).Q1Q3  P2: B(t+1).s0  P3: B(t+1).s1  P4: A(t+2).Q0Q2
// Single counted drain vmcnt(2) at P4. Raw barriers (no sched_barrier pinning).
template<int N, int K, bool ACT, bool OUTF32>
__global__ __launch_bounds__(512, 2) void gemm_mlp(
    const u16* __restrict__ A, const u16* __restrict__ Bt,
    u16* __restrict__ Ch, float* __restrict__ Cf)
{
    constexpr int M = 65536;
    constexpr int NT = K / 64;
    constexpr int NTN = N / 256;
    constexpr int NWG = (M / 256) * NTN;

    __shared__ u16 sA[2][256 * 64];
    __shared__ u16 sB[2][2 * 128 * 64];

    const int bid = blockIdx.x;
    const int wk = (bid & 7) * (NWG >> 3) + (bid >> 3);   // bijective: NWG%8==0
    const int tm = wk / NTN, tn = wk % NTN;
    const long m0 = (long)tm * 256;
    const int n0 = tn * 256;

    const int tid = threadIdx.x;
    const int lane = tid & 63;
    const int wid = tid >> 6;
    const int wm = (wid >> 2) * 128;   // 2 M-waves
    const int wn = (wid & 3) * 64;     // 4 N-waves

    // ---- staging addresses (inverse-swizzled global source, linear LDS dest) ----
    const int r8 = tid >> 3;
    const int gcol = ((tid & 7) ^ (r8 & 7)) * 8;
    const u16* Abase = A + (m0 + r8) * (size_t)K + gcol;
    const u16* Bbase = Bt + (size_t)(n0 + ((r8 >> 5) * 64 + (r8 & 31))) * K + gcol;
    const int dst8 = tid * 8;

    // hoisted per-quarter bases (loop adds only t*64 elements)
    const u16* Aq0 = Abase;
    const u16* Aq1 = Abase + (size_t)64 * K;
    const u16* Aq2 = Abase + (size_t)128 * K;
    const u16* Aq3 = Abase + (size_t)192 * K;
    const u16* B00 = Bbase;                      // s0,c0
    const u16* B01 = Bbase + (size_t)128 * K;    // s0,c1
    const u16* B10 = Bbase + (size_t)32 * K;     // s1,c0
    const u16* B11 = Bbase + (size_t)160 * K;    // s1,c1

    auto stA = [&](int buf, const u16* base, int t, int q) {
        gld_lds16(base + (size_t)t * 64, &sA[buf][q * 4096 + dst8]);
    };
    auto stB = [&](int buf, const u16* base, int t, int s, int c) {
        gld_lds16(base + (size_t)t * 64, &sB[buf][s * 8192 + c * 4096 + dst8]);
    };

    // ---- fragment read bases (swizzled) ----
    const int rbase = lane & 15;
    const int co0 = ((lane >> 4) ^ (lane & 7)) * 8;
    const int arow0 = (wm + rbase) * 64 + co0;
    const int brow0 = ((wn >> 6) * 32 + rbase) * 64 + co0;

    f32x4 acc[8][4] = {};
    f16x8 a[4][2], bq[2][2][2];

    auto ldA = [&](int buf, int qm) {
#pragma unroll
        for (int i = 0; i < 4; i++) {
            int base = arow0 + (qm * 64 + i * 16) * 64;
            a[i][0] = *(const f16x8*)&sA[buf][base];
            a[i][1] = *(const f16x8*)&sA[buf][base ^ 32];
        }
    };
    auto ldB = [&](int buf, int qn) {
#pragma unroll
        for (int j2 = 0; j2 < 2; j2++) {
            int base = brow0 + qn * 8192 + j2 * 1024;
            bq[qn][j2][0] = *(const f16x8*)&sB[buf][base];
            bq[qn][j2][1] = *(const f16x8*)&sB[buf][base ^ 32];
        }
    };
    auto mmaq = [&](int qm, int qn) {
        __builtin_amdgcn_s_setprio(1);
#pragma unroll
        for (int kk = 0; kk < 2; kk++)
#pragma unroll
            for (int i = 0; i < 4; i++)
#pragma unroll
                for (int j2 = 0; j2 < 2; j2++)
                    acc[qm * 4 + i][qn * 2 + j2] = __builtin_amdgcn_mfma_f32_16x16x32_f16(
                        a[i][kk], bq[qn][j2][kk], acc[qm * 4 + i][qn * 2 + j2], 0, 0, 0);
        __builtin_amdgcn_s_setprio(0);
    };
    auto bar = [&]() {
        asm volatile("" ::: "memory");
        __builtin_amdgcn_s_barrier();
        asm volatile("" ::: "memory");
    };

    // ---- prologue: tile0 full + A(1).Q0Q2 in flight; drain to 2 ----
    stA(0, Aq0, 0, 0); stA(0, Aq2, 0, 2);
    stB(0, B00, 0, 0, 0); stB(0, B01, 0, 0, 1);
    stB(0, B10, 0, 1, 0); stB(0, B11, 0, 1, 1);
    stA(0, Aq1, 0, 1); stA(0, Aq3, 0, 3);
    stA(1, Aq0, 1, 0); stA(1, Aq2, 1, 2);
    asm volatile("s_waitcnt vmcnt(2)" ::: "memory");
    bar();

    // ---- main loop: tiles 0 .. NT-3 ----
#pragma unroll 2
    for (int t = 0; t < NT - 2; t++) {
        const int cur = t & 1, nxt = cur ^ 1;
        // P1
        stA(nxt, Aq1, t + 1, 1); stA(nxt, Aq3, t + 1, 3);
        ldA(cur, 0); ldB(cur, 0);
        bar();
        mmaq(0, 0);
        // P2
        stB(nxt, B00, t + 1, 0, 0); stB(nxt, B01, t + 1, 0, 1);
        ldB(cur, 1);
        bar();
        mmaq(0, 1);
        // P3
        stB(nxt, B10, t + 1, 1, 0); stB(nxt, B11, t + 1, 1, 1);
        ldA(cur, 1);
        bar();
        mmaq(1, 0);
        // P4
        stA(cur, Aq0, t + 2, 0); stA(cur, Aq2, t + 2, 2);
        asm volatile("s_waitcnt vmcnt(2)" ::: "memory");
        bar();
        mmaq(1, 1);
    }
    // ---- t = NT-2 (no t+2 A-stage; drain all) ----
    {
        const int t = NT - 2, cur = t & 1, nxt = cur ^ 1;
        stA(nxt, Aq1, t + 1, 1); stA(nxt, Aq3, t + 1, 3);
        ldA(cur, 0); ldB(cur, 0);
        bar();
        mmaq(0, 0);
        stB(nxt, B00, t + 1, 0, 0); stB(nxt, B01, t + 1, 0, 1);
        ldB(cur, 1);
        bar();
        mmaq(0, 1);
        stB(nxt, B10, t + 1, 1, 0); stB(nxt, B11, t + 1, 1, 1);
        ldA(cur, 1);
        bar();
        mmaq(1, 0);
        asm volatile("s_waitcnt vmcnt(0)" ::: "memory");
        bar();
        mmaq(1, 1);
    }
    // ---- t = NT-1: barrier-free (no LDS writes remain) ----
    {
        const int cur = (NT - 1) & 1;
        ldA(cur, 0); ldB(cur, 0);
        mmaq(0, 0);
        ldB(cur, 1);
        mmaq(0, 1);
        ldA(cur, 1);
        mmaq(1, 0);
        mmaq(1, 1);
    }

    // ---- epilogue: C layout col = lane&15, row = (lane>>4)*4 + reg ----
    const long crow0 = m0 + wm + ((lane >> 4) << 2);
    const int ccol0 = n0 + wn + (lane & 15);
#pragma unroll
    for (int fi = 0; fi < 8; fi++) {
#pragma unroll
        for (int r = 0; r < 4; r++) {
            const size_t rowoff = (size_t)(crow0 + fi * 16 + r) * N;
#pragma unroll
            for (int fj = 0; fj < 4; fj++) {
                float v = acc[fi][fj][r];
                if (ACT) v = fmaxf(v, 0.f) + __logf(1.f + __expf(-fabsf(v)));
                if (OUTF32) Cf[rowoff + ccol0 + fj * 16] = v;
                else        Ch[rowoff + ccol0 + fj * 16] = f2h(v);
            }
        }
    }
}

// ---------------- launch ----------------
extern "C" void kernel_launch(void* const* d_in, const int* in_sizes, int n_in,
                              void* d_out, int out_size, void* d_ws, size_t ws_size,
                              hipStream_t stream) {
    const float* x  = (const float*)d_in[0];
    const float* v1 = (const float*)d_in[1];
    const float* g1 = (const float*)d_in[2];
    const float* v2 = (const float*)d_in[3];
    const float* g2 = (const float*)d_in[4];
    const float* v3 = (const float*)d_in[5];
    const float* g3 = (const float*)d_in[6];
    const float* v4 = (const float*)d_in[7];
    const float* g4 = (const float*)d_in[8];
    const float* v5 = (const float*)d_in[9];
    const float* g5 = (const float*)d_in[10];
    float* out = (float*)d_out;

    const int M = 65536;
    char* ws = (char*)d_ws;
    u16* bufA = (u16*)(ws);                          // 128 MB
    u16* bufB = (u16*)(ws + 0x8000000ULL);           // 128 MB
    u16* w1T  = (u16*)(ws + 0x10000000ULL);
    u16* w2T  = w1T + 1024 * 512;
    u16* w3T  = w2T + 1024 * 1024;
    u16* w4T  = w3T + 1024 * 1024;
    u16* w5T  = w4T + 1024 * 1024;

    cvt_x_kernel<<<(M * 512) / (256 * 8), 256, 0, stream>>>((const float4*)x, bufB);

    wn_fused<<<1024 / 64, 256, 0, stream>>>(v1, g1, w1T, 512, 1024);
    wn_fused<<<1024 / 64, 256, 0, stream>>>(v2, g2, w2T, 1024, 1024);
    wn_fused<<<1024 / 64, 256, 0, stream>>>(v3, g3, w3T, 1024, 1024);
    wn_fused<<<1024 / 64, 256, 0, stream>>>(v4, g4, w4T, 1024, 1024);
    wn_fused<<<512 / 64, 256, 0, stream>>>(v5, g5, w5T, 1024, 512);

    gemm_mlp<1024, 512,  true,  false><<<1024, 512, 0, stream>>>(bufB, w1T, bufA, nullptr);
    gemm_mlp<1024, 1024, true,  false><<<1024, 512, 0, stream>>>(bufA, w2T, bufB, nullptr);
    gemm_mlp<1024, 1024, true,  false><<<1024, 512, 0, stream>>>(bufB, w3T, bufA, nullptr);
    gemm_mlp<1024, 1024, true,  false><<<1024, 512, 0, stream>>>(bufA, w4T, bufB, nullptr);
    gemm_mlp<512,  1024, false, true ><<<512,  512, 0, stream>>>(bufB, w5T, nullptr, out);

    (void)in_sizes; (void)n_in; (void)out_size; (void)ws_size;
}

// Round 4
// 714.400 us; speedup vs baseline: 1.9376x; 1.9376x over previous
//
#include <hip/hip_runtime.h>
#include <hip/hip_bf16.h>
#include <cstdint>

typedef unsigned short u16;
typedef __attribute__((ext_vector_type(8))) _Float16 f16x8;
typedef __attribute__((ext_vector_type(4))) float f32x4;
typedef __attribute__((ext_vector_type(8))) unsigned short u16x8;

typedef const __attribute__((address_space(1))) void* gas1p;
typedef __attribute__((address_space(3))) void* las3p;

__device__ __forceinline__ void gld_lds16(const void* g, void* l) {
    __builtin_amdgcn_global_load_lds((gas1p)g, (las3p)l, 16, 0, 0);
}

__device__ __forceinline__ u16 f2h(float f) {
    _Float16 h = (_Float16)f;
    return __builtin_bit_cast(u16, h);
}

// ---------------- prep: x fp32 -> fp16 ----------------
__global__ void cvt_x_kernel(const float4* __restrict__ x, u16* __restrict__ xb) {
    size_t i = (size_t)blockIdx.x * blockDim.x + threadIdx.x;
    float4 a = x[2 * i];
    float4 b = x[2 * i + 1];
    u16x8 o;
    o[0] = f2h(a.x); o[1] = f2h(a.y); o[2] = f2h(a.z); o[3] = f2h(a.w);
    o[4] = f2h(b.x); o[5] = f2h(b.y); o[6] = f2h(b.z); o[7] = f2h(b.w);
    *(u16x8*)&xb[i * 8] = o;
}

// ---------------- prep: weight norm, all 5 layers in 2 launches ----------------
struct WnDesc {
    const float* v; const float* g; u16* wT; float* partial;
    int K; int N; int blk0;   // blk0 = cumulative first flat-block index
};
struct WnPack { WnDesc d[5]; int nlayer; };

// pass 1: partial[seg][n] = sum over seg's K/8 rows of v[k][n]^2
// per layer: (N/64) * 8 blocks of 256 threads (64 cols x 4 rows-threads)
__global__ void wn_partial_all(WnPack p) {
    int b = blockIdx.x;
    int l = 0;
    while (l + 1 < p.nlayer && b >= p.d[l + 1].blk0) l++;
    const WnDesc& d = p.d[l];
    int lb = b - d.blk0;
    int nbx = d.N >> 6;
    int bx = lb % nbx, seg = lb / nbx;

    int lane = threadIdx.x & 63;
    int tr = threadIdx.x >> 6;
    int n = bx * 64 + lane;
    int kseg = d.K >> 3;
    int kbeg = seg * kseg;
    float s = 0.f;
    for (int k = kbeg + tr; k < kbeg + kseg; k += 4) {
        float x = d.v[(size_t)k * d.N + n];
        s += x * x;
    }
    __shared__ float red[4][64];
    red[tr][lane] = s;
    __syncthreads();
    if (tr == 0)
        d.partial[seg * d.N + n] = red[0][lane] + red[1][lane] + red[2][lane] + red[3][lane];
}

// pass 2: wT[n][k] = fp16(v[k][n] * g[n]/sqrt(sum partials)), same partition
__global__ void wn_write_all(WnPack p) {
    int b = blockIdx.x;
    int l = 0;
    while (l + 1 < p.nlayer && b >= p.d[l + 1].blk0) l++;
    const WnDesc& d = p.d[l];
    int lb = b - d.blk0;
    int nbx = d.N >> 6;
    int bx = lb % nbx, seg = lb / nbx;

    int lane = threadIdx.x & 63;
    int tr = threadIdx.x >> 6;
    int n = bx * 64 + lane;
    float s = 0.f;
#pragma unroll
    for (int i = 0; i < 8; i++) s += d.partial[i * d.N + n];
    float sc = d.g[n] / sqrtf(s);

    int kseg = d.K >> 3;
    int kbeg = seg * kseg;
    for (int k = kbeg + tr; k < kbeg + kseg; k += 4)
        d.wT[(size_t)n * d.K + k] = f2h(d.v[(size_t)k * d.N + n] * sc);
}

// ---------------- main GEMM: 256x256 tile, BK=64, 8 waves, 4-phase schedule ----
// (unchanged from R3 — schedule delivered ~-25% GEMM time per timing inference)
template<int N, int K, bool ACT, bool OUTF32>
__global__ __launch_bounds__(512, 2) void gemm_mlp(
    const u16* __restrict__ A, const u16* __restrict__ Bt,
    u16* __restrict__ Ch, float* __restrict__ Cf)
{
    constexpr int M = 65536;
    constexpr int NT = K / 64;
    constexpr int NTN = N / 256;
    constexpr int NWG = (M / 256) * NTN;

    __shared__ u16 sA[2][256 * 64];
    __shared__ u16 sB[2][2 * 128 * 64];

    const int bid = blockIdx.x;
    const int wk = (bid & 7) * (NWG >> 3) + (bid >> 3);   // bijective: NWG%8==0
    const int tm = wk / NTN, tn = wk % NTN;
    const long m0 = (long)tm * 256;
    const int n0 = tn * 256;

    const int tid = threadIdx.x;
    const int lane = tid & 63;
    const int wid = tid >> 6;
    const int wm = (wid >> 2) * 128;
    const int wn = (wid & 3) * 64;

    const int r8 = tid >> 3;
    const int gcol = ((tid & 7) ^ (r8 & 7)) * 8;
    const u16* Abase = A + (m0 + r8) * (size_t)K + gcol;
    const u16* Bbase = Bt + (size_t)(n0 + ((r8 >> 5) * 64 + (r8 & 31))) * K + gcol;
    const int dst8 = tid * 8;

    const u16* Aq0 = Abase;
    const u16* Aq1 = Abase + (size_t)64 * K;
    const u16* Aq2 = Abase + (size_t)128 * K;
    const u16* Aq3 = Abase + (size_t)192 * K;
    const u16* B00 = Bbase;
    const u16* B01 = Bbase + (size_t)128 * K;
    const u16* B10 = Bbase + (size_t)32 * K;
    const u16* B11 = Bbase + (size_t)160 * K;

    auto stA = [&](int buf, const u16* base, int t, int q) {
        gld_lds16(base + (size_t)t * 64, &sA[buf][q * 4096 + dst8]);
    };
    auto stB = [&](int buf, const u16* base, int t, int s, int c) {
        gld_lds16(base + (size_t)t * 64, &sB[buf][s * 8192 + c * 4096 + dst8]);
    };

    const int rbase = lane & 15;
    const int co0 = ((lane >> 4) ^ (lane & 7)) * 8;
    const int arow0 = (wm + rbase) * 64 + co0;
    const int brow0 = ((wn >> 6) * 32 + rbase) * 64 + co0;

    f32x4 acc[8][4] = {};
    f16x8 a[4][2], bq[2][2][2];

    auto ldA = [&](int buf, int qm) {
#pragma unroll
        for (int i = 0; i < 4; i++) {
            int base = arow0 + (qm * 64 + i * 16) * 64;
            a[i][0] = *(const f16x8*)&sA[buf][base];
            a[i][1] = *(const f16x8*)&sA[buf][base ^ 32];
        }
    };
    auto ldB = [&](int buf, int qn) {
#pragma unroll
        for (int j2 = 0; j2 < 2; j2++) {
            int base = brow0 + qn * 8192 + j2 * 1024;
            bq[qn][j2][0] = *(const f16x8*)&sB[buf][base];
            bq[qn][j2][1] = *(const f16x8*)&sB[buf][base ^ 32];
        }
    };
    auto mmaq = [&](int qm, int qn) {
        __builtin_amdgcn_s_setprio(1);
#pragma unroll
        for (int kk = 0; kk < 2; kk++)
#pragma unroll
            for (int i = 0; i < 4; i++)
#pragma unroll
                for (int j2 = 0; j2 < 2; j2++)
                    acc[qm * 4 + i][qn * 2 + j2] = __builtin_amdgcn_mfma_f32_16x16x32_f16(
                        a[i][kk], bq[qn][j2][kk], acc[qm * 4 + i][qn * 2 + j2], 0, 0, 0);
        __builtin_amdgcn_s_setprio(0);
    };
    auto bar = [&]() {
        asm volatile("" ::: "memory");
        __builtin_amdgcn_s_barrier();
        asm volatile("" ::: "memory");
    };

    stA(0, Aq0, 0, 0); stA(0, Aq2, 0, 2);
    stB(0, B00, 0, 0, 0); stB(0, B01, 0, 0, 1);
    stB(0, B10, 0, 1, 0); stB(0, B11, 0, 1, 1);
    stA(0, Aq1, 0, 1); stA(0, Aq3, 0, 3);
    stA(1, Aq0, 1, 0); stA(1, Aq2, 1, 2);
    asm volatile("s_waitcnt vmcnt(2)" ::: "memory");
    bar();

#pragma unroll 2
    for (int t = 0; t < NT - 2; t++) {
        const int cur = t & 1, nxt = cur ^ 1;
        stA(nxt, Aq1, t + 1, 1); stA(nxt, Aq3, t + 1, 3);
        ldA(cur, 0); ldB(cur, 0);
        bar();
        mmaq(0, 0);
        stB(nxt, B00, t + 1, 0, 0); stB(nxt, B01, t + 1, 0, 1);
        ldB(cur, 1);
        bar();
        mmaq(0, 1);
        stB(nxt, B10, t + 1, 1, 0); stB(nxt, B11, t + 1, 1, 1);
        ldA(cur, 1);
        bar();
        mmaq(1, 0);
        stA(cur, Aq0, t + 2, 0); stA(cur, Aq2, t + 2, 2);
        asm volatile("s_waitcnt vmcnt(2)" ::: "memory");
        bar();
        mmaq(1, 1);
    }
    {
        const int t = NT - 2, cur = t & 1, nxt = cur ^ 1;
        stA(nxt, Aq1, t + 1, 1); stA(nxt, Aq3, t + 1, 3);
        ldA(cur, 0); ldB(cur, 0);
        bar();
        mmaq(0, 0);
        stB(nxt, B00, t + 1, 0, 0); stB(nxt, B01, t + 1, 0, 1);
        ldB(cur, 1);
        bar();
        mmaq(0, 1);
        stB(nxt, B10, t + 1, 1, 0); stB(nxt, B11, t + 1, 1, 1);
        ldA(cur, 1);
        bar();
        mmaq(1, 0);
        asm volatile("s_waitcnt vmcnt(0)" ::: "memory");
        bar();
        mmaq(1, 1);
    }
    {
        const int cur = (NT - 1) & 1;
        ldA(cur, 0); ldB(cur, 0);
        mmaq(0, 0);
        ldB(cur, 1);
        mmaq(0, 1);
        ldA(cur, 1);
        mmaq(1, 0);
        mmaq(1, 1);
    }

    const long crow0 = m0 + wm + ((lane >> 4) << 2);
    const int ccol0 = n0 + wn + (lane & 15);
#pragma unroll
    for (int fi = 0; fi < 8; fi++) {
#pragma unroll
        for (int r = 0; r < 4; r++) {
            const size_t rowoff = (size_t)(crow0 + fi * 16 + r) * N;
#pragma unroll
            for (int fj = 0; fj < 4; fj++) {
                float v = acc[fi][fj][r];
                if (ACT) v = fmaxf(v, 0.f) + __logf(1.f + __expf(-fabsf(v)));
                if (OUTF32) Cf[rowoff + ccol0 + fj * 16] = v;
                else        Ch[rowoff + ccol0 + fj * 16] = f2h(v);
            }
        }
    }
}

// ---------------- launch ----------------
extern "C" void kernel_launch(void* const* d_in, const int* in_sizes, int n_in,
                              void* d_out, int out_size, void* d_ws, size_t ws_size,
                              hipStream_t stream) {
    const float* x  = (const float*)d_in[0];
    const float* v1 = (const float*)d_in[1];
    const float* g1 = (const float*)d_in[2];
    const float* v2 = (const float*)d_in[3];
    const float* g2 = (const float*)d_in[4];
    const float* v3 = (const float*)d_in[5];
    const float* g3 = (const float*)d_in[6];
    const float* v4 = (const float*)d_in[7];
    const float* g4 = (const float*)d_in[8];
    const float* v5 = (const float*)d_in[9];
    const float* g5 = (const float*)d_in[10];
    float* out = (float*)d_out;

    const int M = 65536;
    char* ws = (char*)d_ws;
    u16* bufA = (u16*)(ws);                          // 128 MB
    u16* bufB = (u16*)(ws + 0x8000000ULL);           // 128 MB
    u16* w1T  = (u16*)(ws + 0x10000000ULL);
    u16* w2T  = w1T + 1024 * 512;
    u16* w3T  = w2T + 1024 * 1024;
    u16* w4T  = w3T + 1024 * 1024;
    u16* w5T  = w4T + 1024 * 1024;
    float* part = (float*)(ws + 0x10800000ULL);      // 5 x 8 x 1024 f32

    cvt_x_kernel<<<(M * 512) / (256 * 8), 256, 0, stream>>>((const float4*)x, bufB);

    // blocks per layer: (N/64)*8
    WnPack pk;
    int cum = 0;
    auto mk = [&](int i, const float* v, const float* g, u16* wT, int K, int N) {
        pk.d[i] = WnDesc{v, g, wT, part + i * 8 * 1024, K, N, cum};
        cum += (N / 64) * 8;
    };
    mk(0, v1, g1, w1T, 512, 1024);
    mk(1, v2, g2, w2T, 1024, 1024);
    mk(2, v3, g3, w3T, 1024, 1024);
    mk(3, v4, g4, w4T, 1024, 1024);
    mk(4, v5, g5, w5T, 1024, 512);
    pk.nlayer = 5;

    wn_partial_all<<<cum, 256, 0, stream>>>(pk);
    wn_write_all<<<cum, 256, 0, stream>>>(pk);

    gemm_mlp<1024, 512,  true,  false><<<1024, 512, 0, stream>>>(bufB, w1T, bufA, nullptr);
    gemm_mlp<1024, 1024, true,  false><<<1024, 512, 0, stream>>>(bufA, w2T, bufB, nullptr);
    gemm_mlp<1024, 1024, true,  false><<<1024, 512, 0, stream>>>(bufB, w3T, bufA, nullptr);
    gemm_mlp<1024, 1024, true,  false><<<1024, 512, 0, stream>>>(bufA, w4T, bufB, nullptr);
    gemm_mlp<512,  1024, false, true ><<<512,  512, 0, stream>>>(bufB, w5T, nullptr, out);

    (void)in_sizes; (void)n_in; (void)out_size; (void)ws_size;
}